// Round 1
// baseline (781.295 us; speedup 1.0000x reference)
//
#include <hip/hip_runtime.h>
#include <math.h>

#define NSC   8
#define WLEN  64
#define S_LEN 4096
#define FEAT  64
#define TB    64   // t-tile per block
#define KC    64   // k-chunk

struct ScaleParams {
  int   L[NSC];     // dilated wavelet lengths
  float step[NSC];  // (float)(63.0 / (L-1))   -- interp position step
  float isq[NSC];   // (float)(1.0 / sqrt(scale))
};

// Block: 256 threads = 4 waves. Wave tw owns t in [t0+16*tw, t0+16*tw+15], lane = f.
// Each thread: 16 accumulators + 16-entry sliding signal window in registers.
__global__ __launch_bounds__(256, 4) void wavelet_conv_kernel(
    const float* __restrict__ sig,   // (B, S, F)
    const float* __restrict__ mw,    // (8, 64) mother wavelets
    const float* __restrict__ sw,    // (8,) scale weights
    float* __restrict__ out,         // (B, 8, S, F)
    ScaleParams p)
{
  __shared__ float lds_sig[127][FEAT];  // rows rbase..rbase+126
  __shared__ float lds_w[KC];           // dilated wavelet chunk
  __shared__ float lds_mw[WLEN];        // mother wavelet for this scale

  const int tile = 63 - (int)blockIdx.x;   // heavy (late-t) tiles first
  const int isc  = 7  - (int)blockIdx.y;   // heavy scales first
  const int b    = blockIdx.z;

  const int   L   = p.L[isc];
  const float stp = p.step[isc];
  const float isq = p.isq[isc];
  const int   t0  = tile * TB;

  const int tid  = threadIdx.x;
  const int f    = tid & 63;
  const int tw   = tid >> 6;
  const int tw16 = tw * 16;

  if (tid < WLEN) lds_mw[tid] = mw[isc * WLEN + tid];
  const float swi = sw[isc];

  const float* sigb = sig + (size_t)b * S_LEN * FEAT;

  float acc[16];
  #pragma unroll
  for (int j = 0; j < 16; ++j) acc[j] = 0.f;

  // chunks with kc > t0+63 contribute only zeros (t-k < 0) -> skip
  const int nch = min((L + KC - 1) / KC, tile + 1);

  for (int c = 0; c < nch; ++c) {
    const int kc    = c * KC;
    const int rbase = t0 - kc - 63;

    __syncthreads();  // protect previous chunk's LDS reads (also covers lds_mw init)

    // ---- stage dilated-wavelet chunk (computed on the fly, mimics jnp.interp in f32)
    if (tid < KC) {
      int k = kc + tid;
      float val = 0.f;
      if (k < L) {
        float pos = (float)k * stp;
        float r;
        if (pos >= 63.f) {
          r = lds_mw[63];
        } else {
          int   ii   = (int)pos;           // pos >= 0
          float frac = pos - (float)ii;
          r = fmaf(frac, lds_mw[ii + 1] - lds_mw[ii], lds_mw[ii]);
        }
        val = r * isq * swi;
      }
      lds_w[tid] = val;
    }

    // ---- stage 127 signal rows [rbase, rbase+126], zeros for r < 0
    #pragma unroll
    for (int q = 0; q < 8; ++q) {
      int idx = tid + 256 * q;             // float4 index; row = idx>>4, quad = idx&15
      if (idx < 127 * 16) {
        int r = rbase + (idx >> 4);
        float4 v4 = make_float4(0.f, 0.f, 0.f, 0.f);
        if (r >= 0)
          v4 = *(const float4*)(sigb + ((size_t)r << 6) + ((idx & 15) << 2));
        *(float4*)&lds_sig[idx >> 4][(idx & 15) << 2] = v4;
      }
    }
    __syncthreads();

    // ---- sliding-window inner loop: 1 LDS read + 16 FMAs per tap
    // window invariant at tap kap: logical v[j] = sig row (t0 + tw16 + j - kc - kap),
    // stored in v[(j - kap) & 15]
    float v[16];
    #pragma unroll
    for (int j = 0; j < 16; ++j) v[j] = lds_sig[tw16 + 63 + j][f];

    #pragma unroll
    for (int kap = 0; kap < KC; ++kap) {
      float wk = lds_w[kap];
      #pragma unroll
      for (int j = 0; j < 16; ++j)
        acc[j] = fmaf(wk, v[(j + ((64 - kap) & 15)) & 15], acc[j]);
      if (kap < KC - 1)
        v[(15 - kap) & 15] = lds_sig[tw16 + 62 - kap][f];
    }
  }

  float* outp = out + ((((size_t)b * NSC + isc) * S_LEN) + t0 + tw16) * FEAT + f;
  #pragma unroll
  for (int j = 0; j < 16; ++j) outp[(size_t)j * FEAT] = acc[j];
}

extern "C" void kernel_launch(void* const* d_in, const int* in_sizes, int n_in,
                              void* d_out, int out_size, void* d_ws, size_t ws_size,
                              hipStream_t stream) {
  const float* sig = (const float*)d_in[0];
  const float* mw  = (const float*)d_in[1];
  const float* sw  = (const float*)d_in[2];
  float*       out = (float*)d_out;

  // Replicate np.logspace(0, log10(64), 8) + int(64*scale) exactly (host libm, f64):
  // linspace: y[i] = i * (stop/7) for i<7, y[7] = stop; scales = 10**y.
  ScaleParams p;
  const double lg = log10(64.0);
  const double st = lg / 7.0;
  for (int i = 0; i < NSC; ++i) {
    double y = (i == 7) ? lg : (double)i * st;
    double s = pow(10.0, y);
    int L = (int)(64.0 * s);               // Python int() truncation
    p.L[i]    = L;
    p.step[i] = (float)(63.0 / (double)(L - 1));
    p.isq[i]  = (float)(1.0 / sqrt(s));
  }

  dim3 grid(S_LEN / TB, NSC, 16);  // (64, 8, 16)
  wavelet_conv_kernel<<<grid, 256, 0, stream>>>(sig, mw, sw, out, p);
}

// Round 2
// 96.269 us; speedup vs baseline: 8.1157x; 8.1157x over previous
//
#include <hip/hip_runtime.h>
#include <hip/hip_bf16.h>
#include <math.h>

typedef __attribute__((ext_vector_type(8))) short bf16x8;
typedef __attribute__((ext_vector_type(4))) float f32x4;
typedef __attribute__((ext_vector_type(4))) unsigned int u32x4;

#define NSC    8
#define SLEN   4096
#define FEAT   64
#define W_TOT  10368      // padded elems per wavelet copy (sum of round8(L+160))
#define W_TOT2 22528      // 2 copies + tail pad -> 45056 bytes (11 * 4096)
#define SROW   72         // padded row length (bf16 elems) in sigT2 / sbuf
#define CHUNK_B 9216      // 64 rows * 72 * 2B per staged chunk

struct WavP  { int off[NSC]; int L[NSC]; float step[NSC]; float isq[NSC]; };
struct MainP { int cact[NSC]; int baseS[NSC]; };

// ---------------- kernel 1: build dilated, reversed, padded wavelets (bf16) ----
// copy0[x] = Rv(x), copy1[x] = Rv(x+1), where Rv(x) = w~[L+96-x] for 97<=x<=L+96 else 0.
// w~(k) = interp(mother, k*step) * (1/sqrt(scale)) * scale_weight   (matches jnp.interp)
__global__ void k_build_wav(const float* __restrict__ mw, const float* __restrict__ sw,
                            __hip_bfloat16* __restrict__ wg, WavP wp)
{
  for (int e = blockIdx.x * 256 + threadIdx.x; e < W_TOT2; e += gridDim.x * 256) {
    float val = 0.f;
    int p = 0, e2 = e;
    if (e2 >= W_TOT) { p = 1; e2 -= W_TOT; }
    if (e2 < W_TOT) {
      int s = 0;
      #pragma unroll
      for (int i = 1; i < NSC; ++i) if (e2 >= wp.off[i]) s = i;
      int x = e2 - wp.off[s] + p;
      int L = wp.L[s];
      if (x >= 97 && x <= L + 96) {
        int k = L + 96 - x;
        float pos = (float)k * wp.step[s];
        int ii = (int)pos;
        float r;
        if (ii >= 63) r = mw[s * 64 + 63];
        else {
          float a = mw[s * 64 + ii];
          r = fmaf(pos - (float)ii, mw[s * 64 + ii + 1] - a, a);
        }
        val = r * wp.isq[s] * sw[s];
      }
    }
    wg[e] = __float2bfloat16(val);
  }
}

// ---------------- kernel 2: signal f32 [b][r][f] -> bf16 [b][rblk][f][72] -------
__global__ __launch_bounds__(256) void k_transpose(const float* __restrict__ sig,
                                                   __hip_bfloat16* __restrict__ sigT2)
{
  __shared__ float t[64][65];
  const int tid = threadIdx.x;
  const float* sp = sig + (size_t)blockIdx.x * 4096;          // (b*64+rblk)*64*64
  for (int idx = tid; idx < 4096; idx += 256)
    t[idx & 63][idx >> 6] = sp[idx];                          // t[f][rl]
  __syncthreads();
  __hip_bfloat16* op = sigT2 + (size_t)blockIdx.x * (64 * SROW);
  for (int idx = tid; idx < 4096; idx += 256) {
    int f = idx >> 6, rr = idx & 63;
    op[f * SROW + rr] = __float2bfloat16(t[f][rr]);
  }
}

// ---------------- kernel 3: banded-Toeplitz MFMA convolution --------------------
// Block = 256 thr = 4 waves; block owns (b, 64-t tile); wave tw owns rows t0+16tw..+15.
// All 8 scales accumulated simultaneously: acc[8][4] f32x4 (M=16, N=64 as 4 frags).
__global__ __launch_bounds__(256, 2) void k_wavelet_mfma(
    const __hip_bfloat16* __restrict__ sigT2,
    const __hip_bfloat16* __restrict__ wavg,
    float* __restrict__ out, MainP P)
{
  __shared__ __align__(16) short ldsW[W_TOT2];
  __shared__ __align__(16) short sbuf[2][64][SROW];

  const int tid = threadIdx.x;
  const int bid = blockIdx.x;
  const int tt  = 63 - (bid >> 4);        // heavy (large t0) tiles first
  const int b   = bid & 15;
  const int t0  = tt * 64;
  const int tw  = tid >> 6;               // wave id
  const int fl  = tid & 15;               // lane&15: A-row / B-col / D-col
  const int g   = (tid >> 4) & 3;         // lane>>4: k-group / D-row-group
  const int lanepart = 8 * g - fl;

  // stage wavelets (45056 B) into LDS, 16B per lane per issue
  {
    const char* gp = (const char*)wavg;
    char* lp = (char*)ldsW;
    #pragma unroll
    for (int it = 0; it < 11; ++it)
      __builtin_amdgcn_global_load_lds(
        (const __attribute__((address_space(1))) void*)(gp + it * 4096 + tid * 16),
        (__attribute__((address_space(3))) void*)(lp + it * 4096 + (tid >> 6) * 1024),
        16, 0, 0);
  }

  const int C = t0 / 64 + 1;              // chunks: rows [t0-64c, t0-64c+63], c=0..C-1
  const char* sgbase = (const char*)(sigT2 + (size_t)(b * 64) * (64 * SROW));

  auto stage = [&](int c) {
    const char* gp = sgbase + (size_t)(t0 / 64 - c) * CHUNK_B;
    char* lp = (char*)&sbuf[c & 1][0][0];
    #pragma unroll
    for (int it = 0; it < 3; ++it) {
      if (it < 2 || tid < 64)             // 9216 B = 2 full passes + wave0
        __builtin_amdgcn_global_load_lds(
          (const __attribute__((address_space(1))) void*)(gp + it * 4096 + tid * 16),
          (__attribute__((address_space(3))) void*)(lp + it * 4096 + (tid >> 6) * 1024),
          16, 0, 0);
    }
  };

  f32x4 acc[NSC][4];
  const f32x4 z = {0.f, 0.f, 0.f, 0.f};
  #pragma unroll
  for (int s = 0; s < NSC; ++s)
    #pragma unroll
    for (int n = 0; n < 4; ++n) acc[s][n] = z;

  stage(0);

  for (int c = 0; c < C; ++c) {
    __syncthreads();                      // completes stage(c) + wavelets
    if (c + 1 < C) stage(c + 1);          // prefetch into other buffer
    const short* sb = &sbuf[c & 1][0][0];
    #pragma unroll
    for (int h = 1; h >= 0; --h) {        // two 32-row k-steps per chunk
      const int c_old = 2 * c + 1 - h;    // 32-row-granular chunk index
      bf16x8 Bf[4];
      #pragma unroll
      for (int n = 0; n < 4; ++n)
        Bf[n] = *(const bf16x8*)(sb + (n * 16 + fl) * SROW + h * 32 + g * 8);
      const int wk = 32 - 16 * tw - 32 * c_old + lanepart;
      #pragma unroll
      for (int s = NSC - 1; s >= 0; --s) {
        if (c_old <= P.cact[s]) {         // wave-uniform; static acc indices
          int yb  = P.baseS[s] + wk;      // element index into copy0
          int pr  = yb & 1;               // odd -> use shifted copy1
          int idx = yb - pr + pr * W_TOT;
          const unsigned int* ap = (const unsigned int*)(ldsW + idx);
          u32x4 au;
          au.x = ap[0]; au.y = ap[1]; au.z = ap[2]; au.w = ap[3];
          bf16x8 Af = __builtin_bit_cast(bf16x8, au);
          acc[s][0] = __builtin_amdgcn_mfma_f32_16x16x32_bf16(Af, Bf[0], acc[s][0], 0, 0, 0);
          acc[s][1] = __builtin_amdgcn_mfma_f32_16x16x32_bf16(Af, Bf[1], acc[s][1], 0, 0, 0);
          acc[s][2] = __builtin_amdgcn_mfma_f32_16x16x32_bf16(Af, Bf[2], acc[s][2], 0, 0, 0);
          acc[s][3] = __builtin_amdgcn_mfma_f32_16x16x32_bf16(Af, Bf[3], acc[s][3], 0, 0, 0);
        }
      }
    }
  }

  // epilogue: D row = 4*g + reg, col = 16n + fl
  const int trow = t0 + tw * 16 + g * 4;
  float* ob = out + (size_t)b * NSC * SLEN * FEAT;
  #pragma unroll
  for (int s = 0; s < NSC; ++s) {
    float* os = ob + (size_t)s * SLEN * FEAT;
    #pragma unroll
    for (int n = 0; n < 4; ++n)
      #pragma unroll
      for (int r = 0; r < 4; ++r)
        os[(size_t)(trow + r) * FEAT + n * 16 + fl] = acc[s][n][r];
  }
}

extern "C" void kernel_launch(void* const* d_in, const int* in_sizes, int n_in,
                              void* d_out, int out_size, void* d_ws, size_t ws_size,
                              hipStream_t stream) {
  const float* sig = (const float*)d_in[0];
  const float* mw  = (const float*)d_in[1];
  const float* sw  = (const float*)d_in[2];
  float*       out = (float*)d_out;

  // workspace layout: [0,45056+slack) wavelets bf16; [65536, +9437184) sigT2 bf16
  __hip_bfloat16* wavg  = (__hip_bfloat16*)d_ws;
  __hip_bfloat16* sigT2 = (__hip_bfloat16*)((char*)d_ws + 65536);

  // host precompute: np.logspace(0, log10(64), 8), L = int(64*scale) (truncation)
  WavP wp; MainP mp;
  const double lg = log10(64.0), st = lg / 7.0;
  int off = 0;
  for (int i = 0; i < NSC; ++i) {
    double y = (i == 7) ? lg : (double)i * st;
    double s = pow(10.0, y);
    int L = (int)(64.0 * s);
    wp.L[i]    = L;
    wp.step[i] = (float)(63.0 / (double)(L - 1));
    wp.isq[i]  = (float)(1.0 / sqrt(s));
    wp.off[i]  = off;
    mp.cact[i]  = (L + 62) >> 5;          // last active 32-row k-step index
    mp.baseS[i] = off + L + 96;           // off_s + K0_s
    off += ((L + 160 + 7) / 8) * 8;       // round8(L+160), sums to W_TOT=10368
  }

  k_build_wav<<<64, 256, 0, stream>>>(mw, sw, wavg, wp);
  k_transpose<<<1024, 256, 0, stream>>>(sig, sigT2);
  k_wavelet_mfma<<<1024, 256, 0, stream>>>(sigT2, wavg, out, mp);
}

// Round 3
// 90.945 us; speedup vs baseline: 8.5908x; 1.0585x over previous
//
#include <hip/hip_runtime.h>
#include <hip/hip_bf16.h>
#include <math.h>

typedef __attribute__((ext_vector_type(8))) short bf16x8;
typedef __attribute__((ext_vector_type(4))) float f32x4;
typedef __attribute__((ext_vector_type(4))) unsigned int u32x4;

#define NSC    8
#define SLEN   4096
#define FEAT   64
#define W_TOT  10368      // padded elems per wavelet copy (sum of round8(L+160))
#define W_TOT2 22528      // 2 copies + tail pad -> 45056 bytes (11 * 4096)
#define SROW   64         // row length (bf16 elems) in sigT2 / sbuf (swizzled)
#define CHUNK_B 8192      // 64 rows * 64 * 2B per staged chunk

struct WavP  { int off[NSC]; int L[NSC]; float step[NSC]; float isq[NSC]; };
struct MainP { int cact[NSC]; int baseS[NSC]; };

// ---------------- kernel 1: build dilated, reversed, padded wavelets (bf16) ----
// copy0[x] = Rv(x), copy1[x] = Rv(x+1), where Rv(x) = w~[L+96-x] for 97<=x<=L+96 else 0.
// w~(k) = interp(mother, k*step) * (1/sqrt(scale)) * scale_weight   (matches jnp.interp)
__global__ void k_build_wav(const float* __restrict__ mw, const float* __restrict__ sw,
                            __hip_bfloat16* __restrict__ wg, WavP wp)
{
  for (int e = blockIdx.x * 256 + threadIdx.x; e < W_TOT2; e += gridDim.x * 256) {
    float val = 0.f;
    int p = 0, e2 = e;
    if (e2 >= W_TOT) { p = 1; e2 -= W_TOT; }
    if (e2 < W_TOT) {
      int s = 0;
      #pragma unroll
      for (int i = 1; i < NSC; ++i) if (e2 >= wp.off[i]) s = i;
      int x = e2 - wp.off[s] + p;
      int L = wp.L[s];
      if (x >= 97 && x <= L + 96) {
        int k = L + 96 - x;
        float pos = (float)k * wp.step[s];
        int ii = (int)pos;
        float r;
        if (ii >= 63) r = mw[s * 64 + 63];
        else {
          float a = mw[s * 64 + ii];
          r = fmaf(pos - (float)ii, mw[s * 64 + ii + 1] - a, a);
        }
        val = r * wp.isq[s] * sw[s];
      }
    }
    wg[e] = __float2bfloat16(val);
  }
}

// ---------------- kernel 2: signal f32 [b][r][f] -> bf16 [b][rblk][f][64] SWIZZLED
// Within each f-row (8 granules of 16B), granule q stores original granule q^(f&7).
// This pre-applies the LDS bank swizzle so global_load_lds can copy linearly (rule 21).
__global__ __launch_bounds__(256) void k_transpose(const float* __restrict__ sig,
                                                   __hip_bfloat16* __restrict__ sigT2)
{
  __shared__ float t[64][65];
  const int tid = threadIdx.x;
  const float* sp = sig + (size_t)blockIdx.x * 4096;          // (b*64+rblk)*64*64
  for (int idx = tid; idx < 4096; idx += 256)
    t[idx & 63][idx >> 6] = sp[idx];                          // t[f][r]
  __syncthreads();
  __hip_bfloat16* op = sigT2 + (size_t)blockIdx.x * 4096;
  for (int idx = tid; idx < 4096; idx += 256) {
    int f = idx >> 6, rr = idx & 63;
    int dst = (f << 6) + ((((rr >> 3) ^ (f & 7)) << 3) | (rr & 7));
    op[dst] = __float2bfloat16(t[f][rr]);
  }
}

// ---------------- kernel 3: banded-Toeplitz MFMA convolution --------------------
// Block = 256 thr = 4 waves; block owns (b, 64-t tile); wave tw owns rows t0+16tw..+15.
// All 8 scales accumulated simultaneously: acc[8][4] f32x4 (M=16, N=64 as 4 frags).
__global__ __launch_bounds__(256, 2) void k_wavelet_mfma(
    const __hip_bfloat16* __restrict__ sigT2,
    const __hip_bfloat16* __restrict__ wavg,
    float* __restrict__ out, MainP P)
{
  __shared__ __align__(16) short ldsW[W_TOT2];
  __shared__ __align__(16) short sbuf[2][64][SROW];

  const int tid = threadIdx.x;
  const int bid = blockIdx.x;
  const int tt  = 63 - (bid >> 4);        // heavy (large t0) tiles first
  const int b   = bid & 15;
  const int t0  = tt * 64;
  const int tw  = tid >> 6;               // wave id
  const int fl  = tid & 15;               // lane&15: A-row / B-col / D-col
  const int g   = (tid >> 4) & 3;         // lane>>4: k-group / D-row-group
  const int lanepart = 8 * g - fl;
  const int fswz = fl & 7;                // row-XOR for swizzled B reads

  // stage wavelets (45056 B) into LDS, 16B per lane per issue
  {
    const char* gp = (const char*)wavg;
    char* lp = (char*)ldsW;
    #pragma unroll
    for (int it = 0; it < 11; ++it)
      __builtin_amdgcn_global_load_lds(
        (const __attribute__((address_space(1))) void*)(gp + it * 4096 + tid * 16),
        (__attribute__((address_space(3))) void*)(lp + it * 4096 + (tid >> 6) * 1024),
        16, 0, 0);
  }

  const int C = t0 / 64 + 1;              // chunks: rows [t0-64c, t0-64c+63], c=0..C-1
  const char* sgbase = (const char*)(sigT2 + (size_t)(b * 64) * 4096);

  auto stage = [&](int c) {
    const char* gp = sgbase + (size_t)(t0 / 64 - c) * CHUNK_B;
    char* lp = (char*)&sbuf[c & 1][0][0];
    #pragma unroll
    for (int it = 0; it < 2; ++it)
      __builtin_amdgcn_global_load_lds(
        (const __attribute__((address_space(1))) void*)(gp + it * 4096 + tid * 16),
        (__attribute__((address_space(3))) void*)(lp + it * 4096 + (tid >> 6) * 1024),
        16, 0, 0);
  };

  f32x4 acc[NSC][4];
  const f32x4 z = {0.f, 0.f, 0.f, 0.f};
  #pragma unroll
  for (int s = 0; s < NSC; ++s)
    #pragma unroll
    for (int n = 0; n < 4; ++n) acc[s][n] = z;

  stage(0);

  for (int c = 0; c < C; ++c) {
    __syncthreads();                      // completes stage(c) + wavelets
    if (c + 1 < C) stage(c + 1);          // prefetch into other buffer
    const short* sb = &sbuf[c & 1][0][0];
    #pragma unroll
    for (int h = 1; h >= 0; --h) {        // two 32-row k-steps per chunk
      const int c_old = 2 * c + 1 - h;    // 32-row-granular chunk index
      // swizzled B-fragment reads: row f = n*16+fl, col granule (h*4+g)^(fl&7)
      const int coff = (((h << 2) + g) ^ fswz) << 3;
      bf16x8 Bf[4];
      #pragma unroll
      for (int n = 0; n < 4; ++n)
        Bf[n] = *(const bf16x8*)(sb + ((n * 16 + fl) << 6) + coff);
      const int wk = 32 - 16 * tw - 32 * c_old + lanepart;
      __builtin_amdgcn_s_setprio(1);
      #pragma unroll
      for (int s = NSC - 1; s >= 0; --s) {
        if (c_old <= P.cact[s]) {         // wave-uniform; static acc indices
          int yb  = P.baseS[s] + wk;      // element index into copy0
          int pr  = yb & 1;               // odd -> use shifted copy1
          int idx = yb - pr + pr * W_TOT;
          const unsigned int* ap = (const unsigned int*)(ldsW + idx);
          u32x4 au;
          au.x = ap[0]; au.y = ap[1]; au.z = ap[2]; au.w = ap[3];
          bf16x8 Af = __builtin_bit_cast(bf16x8, au);
          acc[s][0] = __builtin_amdgcn_mfma_f32_16x16x32_bf16(Af, Bf[0], acc[s][0], 0, 0, 0);
          acc[s][1] = __builtin_amdgcn_mfma_f32_16x16x32_bf16(Af, Bf[1], acc[s][1], 0, 0, 0);
          acc[s][2] = __builtin_amdgcn_mfma_f32_16x16x32_bf16(Af, Bf[2], acc[s][2], 0, 0, 0);
          acc[s][3] = __builtin_amdgcn_mfma_f32_16x16x32_bf16(Af, Bf[3], acc[s][3], 0, 0, 0);
        }
      }
      __builtin_amdgcn_s_setprio(0);
    }
  }

  // epilogue: D row = 4*g + reg, col = 16n + fl
  const int trow = t0 + tw * 16 + g * 4;
  float* ob = out + (size_t)b * NSC * SLEN * FEAT;
  #pragma unroll
  for (int s = 0; s < NSC; ++s) {
    float* os = ob + (size_t)s * SLEN * FEAT;
    #pragma unroll
    for (int n = 0; n < 4; ++n)
      #pragma unroll
      for (int r = 0; r < 4; ++r)
        os[(size_t)(trow + r) * FEAT + n * 16 + fl] = acc[s][n][r];
  }
}

extern "C" void kernel_launch(void* const* d_in, const int* in_sizes, int n_in,
                              void* d_out, int out_size, void* d_ws, size_t ws_size,
                              hipStream_t stream) {
  const float* sig = (const float*)d_in[0];
  const float* mw  = (const float*)d_in[1];
  const float* sw  = (const float*)d_in[2];
  float*       out = (float*)d_out;

  // workspace layout: [0,45056+slack) wavelets bf16; [65536, +8388608) sigT2 bf16
  __hip_bfloat16* wavg  = (__hip_bfloat16*)d_ws;
  __hip_bfloat16* sigT2 = (__hip_bfloat16*)((char*)d_ws + 65536);

  // host precompute: np.logspace(0, log10(64), 8), L = int(64*scale) (truncation)
  WavP wp; MainP mp;
  const double lg = log10(64.0), st = lg / 7.0;
  int off = 0;
  for (int i = 0; i < NSC; ++i) {
    double y = (i == 7) ? lg : (double)i * st;
    double s = pow(10.0, y);
    int L = (int)(64.0 * s);
    wp.L[i]    = L;
    wp.step[i] = (float)(63.0 / (double)(L - 1));
    wp.isq[i]  = (float)(1.0 / sqrt(s));
    wp.off[i]  = off;
    mp.cact[i]  = (L + 62) >> 5;          // last active 32-row k-step index
    mp.baseS[i] = off + L + 96;           // off_s + K0_s
    off += ((L + 160 + 7) / 8) * 8;       // round8(L+160), sums to W_TOT=10368
  }

  k_build_wav<<<64, 256, 0, stream>>>(mw, sw, wavg, wp);
  k_transpose<<<1024, 256, 0, stream>>>(sig, sigT2);
  k_wavelet_mfma<<<1024, 256, 0, stream>>>(sigT2, wavg, out, mp);
}